// Round 5
// baseline (111.109 us; speedup 1.0000x reference)
//
#include <hip/hip_runtime.h>
#include <hip/hip_bf16.h>

// Problem: B=16384, D=4096, fp32.
// out = mean_i( sum_j w[j] * |in[i,j] - t[i,j]| )
// Memory-bound: 536.9 MB of HBM reads. Floor ~85 us at 6.3 TB/s.
//
// R4 (this round):
//  - single fused kernel: last-block-done tail reduce (atomic counter,
//    zeroed via hipMemsetAsync each launch) -> saves 2nd launch (~3 us)
//  - NTHR=1024/NBLK=512: 512 KiB contiguous stream per block; w index
//    becomes exactly threadIdx.x -> one loop-invariant register
// R3: 88.8 us (block-contiguous chunks, +16%)  R0: 103 us

typedef float v4f __attribute__((ext_vector_type(4)));

#define B_ROWS 16384
#define D_COLS 4096
#define NV4    ((B_ROWS * (long long)D_COLS) / 4)   // 16777216 float4 elements
#define D4     (D_COLS / 4)                          // 1024 float4 per row
#define NBLK   512
#define NTHR   1024
#define CHUNK  (NV4 / NBLK)                          // 32768 float4 = 512 KiB per block
#define ITERS  (CHUNK / NTHR)                        // 32
#define NWAVE  (NTHR / 64)                           // 16

__global__ __launch_bounds__(NTHR) void l1w_fused(
    const v4f* __restrict__ a,
    const v4f* __restrict__ b,
    const v4f* __restrict__ w4,
    float* __restrict__ partial,      // d_ws + 16: NBLK floats
    unsigned int* __restrict__ counter, // d_ws + 0
    float* __restrict__ out)
{
    const int t0 = threadIdx.x;
    const long long base = (long long)blockIdx.x * CHUNK;

    // chunk base is a multiple of D4 (32768 % 1024 == 0) and NTHR==D4,
    // so the w index is (it*1024 + t0) & 1023 == t0 — loop-invariant.
    const v4f wv = w4[t0];

    float acc = 0.0f;
    #pragma unroll 8
    for (int it = 0; it < ITERS; ++it) {
        long long t = base + (long long)it * NTHR + t0;
        v4f av = __builtin_nontemporal_load(&a[t]);
        v4f bv = __builtin_nontemporal_load(&b[t]);
        acc = fmaf(wv.x, fabsf(av.x - bv.x), acc);
        acc = fmaf(wv.y, fabsf(av.y - bv.y), acc);
        acc = fmaf(wv.z, fabsf(av.z - bv.z), acc);
        acc = fmaf(wv.w, fabsf(av.w - bv.w), acc);
    }

    // wave-64 reduce
    #pragma unroll
    for (int off = 32; off > 0; off >>= 1)
        acc += __shfl_down(acc, off, 64);

    __shared__ float s[NWAVE];
    __shared__ bool isLast;
    int lane = t0 & 63;
    int wid  = t0 >> 6;
    if (lane == 0) s[wid] = acc;
    __syncthreads();
    if (t0 == 0) {
        float r = s[0];
        #pragma unroll
        for (int i = 1; i < NWAVE; ++i) r += s[i];
        partial[blockIdx.x] = r;
        __threadfence();                       // make partial visible device-wide
        unsigned prev = atomicAdd(counter, 1u); // device-scope
        isLast = (prev == NBLK - 1);
    }
    __syncthreads();

    if (isLast) {
        // tail reduce: deterministic fixed-order sum of partials
        __threadfence();
        float acc2 = (t0 < NBLK) ? partial[t0] : 0.0f;
        #pragma unroll
        for (int off = 32; off > 0; off >>= 1)
            acc2 += __shfl_down(acc2, off, 64);
        if (lane == 0) s[wid] = acc2;
        __syncthreads();
        if (t0 == 0) {
            float r = s[0];
            #pragma unroll
            for (int i = 1; i < NWAVE; ++i) r += s[i];
            out[0] = r * (1.0f / (float)B_ROWS);
        }
    }
}

extern "C" void kernel_launch(void* const* d_in, const int* in_sizes, int n_in,
                              void* d_out, int out_size, void* d_ws, size_t ws_size,
                              hipStream_t stream) {
    const v4f* a   = (const v4f*)d_in[0];   // inputs  [B, D]
    const v4f* b   = (const v4f*)d_in[1];   // targets [B, D]
    const v4f* w4  = (const v4f*)d_in[2];   // w [D]
    unsigned int* counter = (unsigned int*)d_ws;
    float* partial = (float*)((char*)d_ws + 16);
    float* out     = (float*)d_out;

    hipMemsetAsync(counter, 0, sizeof(unsigned int), stream);
    l1w_fused<<<NBLK, NTHR, 0, stream>>>(a, b, w4, partial, counter, out);
}